// Round 9
// baseline (234.720 us; speedup 1.0000x reference)
//
#include <hip/hip_runtime.h>

using bf16 = __bf16;
typedef bf16 bf16x4 __attribute__((ext_vector_type(4)));
typedef bf16 bf16x8 __attribute__((ext_vector_type(8)));
typedef float f32x4 __attribute__((ext_vector_type(4)));

// ---------------------------------------------------------------- helpers
// GEMM LDS tiles: row stride 192 bf16 (384B, bank-aligned). XOR row&7 into
// element bits [3:5] -> 8 distinct 16B slots per 8 rows.
__device__ __forceinline__ int swz192(int row, int col) {
  return row * 192 + (col ^ ((row & 7) << 3));
}
// attention k tile: 256 rows x 32 bf16 (64B rows). Pack 2 rows per 128B block,
// XOR (row>>1)&3 into col bits [3:4].
__device__ __forceinline__ int qk_idx(int row, int col) {
  return (row >> 1) * 64 + (row & 1) * 32 + (col ^ (((row >> 1) & 3) << 3));
}
// V^T tile: 32 rows(d) x 256 bf16. Rotate n by 16*(d>>3); XOR (d&7)<<3.
__device__ __forceinline__ int vt_idx(int d, int n) {
  return d * 256 + (((n + ((d >> 3) << 4)) & 255) ^ ((d & 7) << 3));
}
// P tile (per wave): 16 rows(q) x 64 bf16 (one K=64 phase) -> XOR r&7 into
// 16B-slot bits (swizzle touches element bits 3-5 only, so 4/8-elt runs at
// 4-aligned offsets stay contiguous for write_b64 / read_b128).
__device__ __forceinline__ int p_idx4(int wv, int r, int c) {
  return wv * 1024 + r * 64 + (c ^ ((r & 7) << 3));
}

#define LOG2E 1.44269504088896f

// ---------------------------------------------------------------- GEMM
// out[m][n] = sum_k A[m][k] * W[n][k] + bias[n];  K = 192 staged whole.
// BM=64, BN=64 (r9: was 128x64 at 73.7KB LDS = 2 blocks/CU; 48KB -> 3/CU and
// the serial staging pole per block halves). 4 waves 2x2, wave = 32x32.
// XCD-co-locating 1D swizzle (r8): x=bid&7, j=bid>>3, m=x+8*(j/NT), n=j%NT.
// NORM_QK: q cols (<192): L2-normalize per-head 32-dim group AND pre-multiply
// by log2e * exp(min(logit_scale,log 100)); k cols ([192,384)): norm only.
template <bool A_BF16, bool OUT_F32, bool NORM_QK, int NT>
__global__ __launch_bounds__(256) void k_gemm(const void* __restrict__ Ap,
                                              const float* __restrict__ W,
                                              const float* __restrict__ bias,
                                              const float* __restrict__ lsc,
                                              void* __restrict__ Op, int Ntot) {
  __shared__ bf16 As[64 * 192];
  __shared__ bf16 Bs[64 * 192];
  const int bid = blockIdx.x;
  const int xcd = bid & 7;
  const int j = bid >> 3;
  const int m0 = (xcd + 8 * (j / NT)) * 64;
  const int n0 = (j % NT) * 64;
  const int t = threadIdx.x;

  if (A_BF16) {
    const bf16* A = (const bf16*)Ap;
#pragma unroll
    for (int i = 0; i < 6; ++i) {
      int f = t + i * 256;
      int row = f / 24, c8 = f % 24;
      bf16x8 v = *reinterpret_cast<const bf16x8*>(&A[(m0 + row) * 192 + c8 * 8]);
      *reinterpret_cast<bf16x8*>(&As[swz192(row, c8 * 8)]) = v;
    }
  } else {
    const float* A = (const float*)Ap;
#pragma unroll
    for (int i = 0; i < 12; ++i) {
      int f = t + i * 256;
      int row = f / 48, c4 = f % 48;
      f32x4 v = *reinterpret_cast<const f32x4*>(&A[(m0 + row) * 192 + c4 * 4]);
      bf16x4 hv;
      hv[0] = (bf16)v[0]; hv[1] = (bf16)v[1]; hv[2] = (bf16)v[2]; hv[3] = (bf16)v[3];
      *reinterpret_cast<bf16x4*>(&As[swz192(row, c4 * 4)]) = hv;
    }
  }
#pragma unroll
  for (int i = 0; i < 12; ++i) {
    int f = t + i * 256;
    int row = f / 48, c4 = f % 48;
    f32x4 v = *reinterpret_cast<const f32x4*>(&W[(n0 + row) * 192 + c4 * 4]);
    bf16x4 hv;
    hv[0] = (bf16)v[0]; hv[1] = (bf16)v[1]; hv[2] = (bf16)v[2]; hv[3] = (bf16)v[3];
    *reinterpret_cast<bf16x4*>(&Bs[swz192(row, c4 * 4)]) = hv;
  }
  __syncthreads();

  const int w = t >> 6, lane = t & 63, lo = lane & 15, hi = lane >> 4;
  const int wm = (w >> 1) * 32, wn = (w & 1) * 32;
  f32x4 acc[2][2];
#pragma unroll
  for (int a = 0; a < 2; ++a)
#pragma unroll
    for (int c = 0; c < 2; ++c) acc[a][c] = f32x4{0.f, 0.f, 0.f, 0.f};

#pragma unroll
  for (int ks = 0; ks < 6; ++ks) {
    const int k0 = ks * 32 + hi * 8;
    bf16x8 af[2], bfr[2];
#pragma unroll
    for (int ri = 0; ri < 2; ++ri)
      af[ri] = *reinterpret_cast<const bf16x8*>(&As[swz192(wm + ri * 16 + lo, k0)]);
#pragma unroll
    for (int ci = 0; ci < 2; ++ci)
      bfr[ci] = *reinterpret_cast<const bf16x8*>(&Bs[swz192(wn + ci * 16 + lo, k0)]);
#pragma unroll
    for (int ri = 0; ri < 2; ++ri)
#pragma unroll
      for (int ci = 0; ci < 2; ++ci)
        acc[ri][ci] = __builtin_amdgcn_mfma_f32_16x16x32_bf16(af[ri], bfr[ci], acc[ri][ci], 0, 0, 0);
  }

  if (NORM_QK) {
    const int cb = n0 + wn;           // wave's 32-col block start (one head group)
    const bool donorm = (cb < 384);   // q or k
    float smul = 1.f;
    if (cb < 192)                     // q: fold logit scale AND log2e (exp->exp2)
      smul = expf(fminf(lsc[cb >> 5], 4.605170185988091f)) * LOG2E;
    const int col0 = cb + lo;
    const float b0 = bias[col0], b1 = bias[col0 + 16];
    bf16* O = (bf16*)Op;
#pragma unroll
    for (int ri = 0; ri < 2; ++ri)
#pragma unroll
      for (int rr = 0; rr < 4; ++rr) {
        float v0 = acc[ri][0][rr] + b0;
        float v1 = acc[ri][1][rr] + b1;
        if (donorm) {
          float ss = v0 * v0 + v1 * v1;
          ss += __shfl_xor(ss, 1, 16);
          ss += __shfl_xor(ss, 2, 16);
          ss += __shfl_xor(ss, 4, 16);
          ss += __shfl_xor(ss, 8, 16);
          const float rn = smul / fmaxf(sqrtf(ss), 1e-12f);
          v0 *= rn;
          v1 *= rn;
        }
        const int row = m0 + wm + ri * 16 + hi * 4 + rr;
        O[row * Ntot + col0] = (bf16)v0;
        O[row * Ntot + col0 + 16] = (bf16)v1;
      }
  } else {
#pragma unroll
    for (int ri = 0; ri < 2; ++ri)
#pragma unroll
      for (int ci = 0; ci < 2; ++ci) {
        const int col = n0 + wn + ci * 16 + lo;
        const float bv = bias[col];
#pragma unroll
        for (int rr = 0; rr < 4; ++rr) {
          const int row = m0 + wm + ri * 16 + hi * 4 + rr;
          const float val = acc[ri][ci][rr] + bv;
          if (OUT_F32)   // final output, never re-read: keep it out of L2
            __builtin_nontemporal_store(val, &((float*)Op)[row * Ntot + col]);
          else
            ((bf16*)Op)[row * Ntot + col] = (bf16)val;
        }
      }
  }
}

// ---------------------------------------------------------------- CPB MLP
// bt[r][h] = (relu(table[r] @ w1^T + b1) @ w2^T)[h]   (961 x 6)
__global__ void k_cpb1(const float* __restrict__ ct, const float* __restrict__ w1,
                       const float* __restrict__ b1, const float* __restrict__ w2,
                       float* __restrict__ bt) {
  int idx = blockIdx.x * 256 + threadIdx.x;
  if (idx >= 961 * 6) return;
  int r = idx / 6, hh = idx % 6;
  float t0 = ct[r * 2], t1 = ct[r * 2 + 1];
  float acc = 0.f;
  for (int j = 0; j < 512; ++j) {
    float hv = fmaf(w1[j * 2], t0, fmaf(w1[j * 2 + 1], t1, b1[j]));
    hv = fmaxf(hv, 0.f);
    acc = fmaf(hv, w2[hh * 512 + j], acc);
  }
  bt[idx] = acc;
}

// biasf[h][i][j] = log2e * 16*sigmoid(bt[rel_index[i][j]][h])  -- NATURAL [q][k] f32
// (r9: swapped-QK^T attn reads 4 consecutive k per lane -> row-major is right)
__global__ void k_cpb2(const float* __restrict__ bt, const int* __restrict__ rel,
                       float* __restrict__ biasf) {
  int idx = blockIdx.x * 256 + threadIdx.x;  // 6*65536 exactly
  int hh = idx >> 16;
  int ij = idx & 65535;
  float v = bt[rel[ij] * 6 + hh];
  biasf[idx] = LOG2E * 16.f / (1.f + expf(-v));
}

// maskb[mb][i][j] = (bf16)(log2e * mask[mb][i][j])  -- straight convert
__global__ void k_maskb(const float* __restrict__ m, bf16* __restrict__ o) {
  int i = blockIdx.x * 256 + threadIdx.x;  // 16384*256 = 4,194,304 exactly
  o[i] = (bf16)(LOG2E * m[i]);
}

// ---------------------------------------------------------------- attention
// One block per (window b, head h), XCD-pinned (bid&7 -> masks [8x,8x+8)).
// 256 threads = 4 waves; LDS 40KB. Max-free fused exp2 softmax.
// r9: SWAPPED QK^T — a = mfma(K, Q, C_in) gives S^T: lane holds q=lane&15,
// k=4*hi+rr (k-consecutive). C_in = bias+mask (MFMA C-operand seeding moves
// the addend adds before the MFMA). P-store: 4x 8B ds_write_b64 per phase
// (was 16 scalar 2B). Softmax: one running sum/lane; reduce = shfl_xor 16,32.
__global__ __launch_bounds__(256) void k_attn(const bf16* __restrict__ qkv,
                                              const bf16* __restrict__ maskb,
                                              const float* __restrict__ biasf,
                                              bf16* __restrict__ aout) {
  __shared__ bf16 ksh[256 * 32];   // 16 KB
  __shared__ bf16 vts[32 * 256];   // 16 KB
  __shared__ bf16 ps[4 * 16 * 64]; //  8 KB

  // ---- XCD-aware remap (bijective): bid -> (b, h)
  const int bid = blockIdx.x;
  const int x = bid & 7, i = bid >> 3;       // i in [0,192)
  const int mb = x * 8 + i / 24;             // 8 masks per XCD
  const int rem = i % 24;
  const int b = (rem / 6) * 64 + mb;         // b & 63 == mb
  const int h = rem % 6;
  const int t = threadIdx.x;

  // ---- staging (k, v): rows t>>2 (+p*64), 16B chunk t&3
  const int rsub = t >> 2;
  const int c4s = t & 3;
#pragma unroll
  for (int p = 0; p < 4; ++p) {
    const int row = p * 64 + rsub;
    const int base = (b * 256 + row) * 576 + h * 32 + c4s * 8;
    *reinterpret_cast<bf16x8*>(&ksh[qk_idx(row, c4s * 8)]) =
        *reinterpret_cast<const bf16x8*>(&qkv[base + 192]);
    bf16x8 v = *reinterpret_cast<const bf16x8*>(&qkv[base + 384]);
#pragma unroll
    for (int jj = 0; jj < 8; ++jj) vts[vt_idx(c4s * 8 + jj, row)] = v[jj];
  }
  __syncthreads();

  const int w = t >> 6, lane = t & 63, lo = lane & 15, hi = lane >> 4;
  const float* bT = biasf + (h << 16);
  const bf16* mT = maskb + (mb << 16);
  const bf16* qbase = qkv + (b * 256) * 576 + h * 32;
  const int kofs = 4 * hi;  // this lane's k sub-offset within a 16-k tile

  // prefetch q fragment for the wave's first row group
  bf16x8 afn = *reinterpret_cast<const bf16x8*>(&qbase[(w * 16 + lo) * 576 + hi * 8]);

  // addend prefetch for rgi=0, ph=0: lane (q = w*16+lo, k = c*16 + 4*hi)
  f32x4 bvp[4];
  bf16x4 mvp[4];
  {
    const int qr0 = w * 16 + lo;
#pragma unroll
    for (int c = 0; c < 4; ++c) {
      bvp[c] = *reinterpret_cast<const f32x4*>(&bT[qr0 * 256 + c * 16 + kofs]);
      mvp[c] = *reinterpret_cast<const bf16x4*>(&mT[qr0 * 256 + c * 16 + kofs]);
    }
  }

  for (int rgi = 0; rgi < 4; ++rgi) {
    const int rg = rgi * 4 + w;  // this wave's 16-row group; private -> no barriers
    const int qrow = rg * 16 + lo;
    const bf16x8 af = afn;
    if (rgi < 3)  // issue next q load early (off the critical path)
      afn = *reinterpret_cast<const bf16x8*>(&qbase[((rg + 4) * 16 + lo) * 576 + hi * 8]);

    f32x4 po0 = {0.f, 0.f, 0.f, 0.f}, po1 = {0.f, 0.f, 0.f, 0.f};
    float psum = 0.f;

#pragma unroll
    for (int ph = 0; ph < 4; ++ph) {
      // ---- consume this phase's prefetched addends; build MFMA C-in
      f32x4 cin[4];
#pragma unroll
      for (int c = 0; c < 4; ++c) {
        cin[c][0] = bvp[c][0] + (float)mvp[c][0];
        cin[c][1] = bvp[c][1] + (float)mvp[c][1];
        cin[c][2] = bvp[c][2] + (float)mvp[c][2];
        cin[c][3] = bvp[c][3] + (float)mvp[c][3];
      }
      // ---- issue NEXT phase's addend loads (hidden under MFMA+exp below)
      if (ph < 3) {
#pragma unroll
        for (int c = 0; c < 4; ++c) {
          const int k0 = (ph + 1) * 64 + c * 16 + kofs;
          bvp[c] = *reinterpret_cast<const f32x4*>(&bT[qrow * 256 + k0]);
          mvp[c] = *reinterpret_cast<const bf16x4*>(&mT[qrow * 256 + k0]);
        }
      } else if (rgi < 3) {  // first phase of the next row group (qrow+64)
#pragma unroll
        for (int c = 0; c < 4; ++c) {
          bvp[c] = *reinterpret_cast<const f32x4*>(&bT[(qrow + 64) * 256 + c * 16 + kofs]);
          mvp[c] = *reinterpret_cast<const bf16x4*>(&mT[(qrow + 64) * 256 + c * 16 + kofs]);
        }
      }
      // ---- S^T quarter: a = mfma(K, Q, C_in) -> lane: q=lo, k=ct*16+4*hi+rr
      bf16x8 kf[4];
#pragma unroll
      for (int c4i = 0; c4i < 4; ++c4i) {
        const int ct = ph * 4 + c4i;
        kf[c4i] = *reinterpret_cast<const bf16x8*>(&ksh[qk_idx(ct * 16 + lo, hi * 8)]);
      }
      f32x4 a[4];
#pragma unroll
      for (int c4i = 0; c4i < 4; ++c4i)
        a[c4i] = __builtin_amdgcn_mfma_f32_16x16x32_bf16(kf[c4i], af, cin[c4i], 0, 0, 0);
      // ---- exp2 + pack 4 bf16 + one 8B LDS store per tile (unnormalized P)
#pragma unroll
      for (int c4i = 0; c4i < 4; ++c4i) {
        bf16x4 hv;
#pragma unroll
        for (int rr = 0; rr < 4; ++rr) {
          const float p = exp2f(a[c4i][rr]);
          psum += p;
          hv[rr] = (bf16)p;
        }
        *reinterpret_cast<bf16x4*>(&ps[p_idx4(w, lo, c4i * 16 + kofs)]) = hv;
      }
      // ---- PV quarter (same-wave LDS producer/consumer; no barrier)
#pragma unroll
      for (int kb = 0; kb < 2; ++kb) {
        const bf16x8 pa = *reinterpret_cast<const bf16x8*>(&ps[p_idx4(w, lo, kb * 32 + hi * 8)]);
        const bf16x8 b0 = *reinterpret_cast<const bf16x8*>(&vts[vt_idx(lo, ph * 64 + kb * 32 + hi * 8)]);
        const bf16x8 b1 = *reinterpret_cast<const bf16x8*>(&vts[vt_idx(16 + lo, ph * 64 + kb * 32 + hi * 8)]);
        po0 = __builtin_amdgcn_mfma_f32_16x16x32_bf16(pa, b0, po0, 0, 0, 0);
        po1 = __builtin_amdgcn_mfma_f32_16x16x32_bf16(pa, b1, po1, 0, 0, 0);
      }
    }
    // ---- total row sum: reduce over the 4 hi-groups (lane's q = qrow)
    float s = psum;
    s += __shfl_xor(s, 16, 64);
    s += __shfl_xor(s, 32, 64);
    s = 1.f / s;
    // redistribute: output lane holds rows rbase+rr = rg*16 + 4*hi + rr;
    // the inverse sum for that row lives at lane (4*hi+rr) (its lo = row)
    const int rbase = rg * 16 + hi * 4;
#pragma unroll
    for (int rr = 0; rr < 4; ++rr) {
      const float rs = __shfl(s, 4 * hi + rr, 64);
      const int ob = (b * 256 + rbase + rr) * 192 + h * 32;
      aout[ob + lo] = (bf16)(po0[rr] * rs);
      aout[ob + 16 + lo] = (bf16)(po1[rr] * rs);
    }
  }
}

// ---------------------------------------------------------------- launcher
extern "C" void kernel_launch(void* const* d_in, const int* in_sizes, int n_in,
                              void* d_out, int out_size, void* d_ws, size_t ws_size,
                              hipStream_t stream) {
  const float* x      = (const float*)d_in[0];
  const float* mask   = (const float*)d_in[1];
  const float* qkv_w  = (const float*)d_in[2];
  const float* qkv_b  = (const float*)d_in[3];
  const float* proj_w = (const float*)d_in[4];
  const float* proj_b = (const float*)d_in[5];
  const float* lsc    = (const float*)d_in[6];
  const float* cpb_w1 = (const float*)d_in[7];
  const float* cpb_b1 = (const float*)d_in[8];
  const float* cpb_w2 = (const float*)d_in[9];
  const float* ctab   = (const float*)d_in[10];
  const int*   relidx = (const int*)d_in[11];

  char* ws = (char*)d_ws;
  bf16*  qkvb  = (bf16*)(ws);                      // 65536*576*2 = 75,497,472
  bf16*  aoutb = (bf16*)(ws + 75497472);           // 65536*192*2 = 25,165,824
  float* biasf = (float*)(ws + 100663296);         // 6*65536*4   =  1,572,864  ([q][k], x log2e)
  bf16*  maskb = (bf16*)(ws + 102236160);          // 64*65536*2  =  8,388,608  ([q][k], x log2e)
  float* bt    = (float*)(ws + 110624768);         // 961*6*4     =     23,064

  k_gemm<false, false, true, 9><<<9216, 256, 0, stream>>>(x, qkv_w, qkv_b, lsc, qkvb, 576);
  k_cpb1<<<23, 256, 0, stream>>>(ctab, cpb_w1, cpb_b1, cpb_w2, bt);
  k_cpb2<<<1536, 256, 0, stream>>>(bt, relidx, biasf);
  k_maskb<<<16384, 256, 0, stream>>>(mask, maskb);
  k_attn<<<1536, 256, 0, stream>>>(qkvb, maskb, biasf, aoutb);
  k_gemm<true, true, false, 3><<<3072, 256, 0, stream>>>(aoutb, proj_w, proj_b, nullptr,
                                                         (float*)d_out, 192);
}

// Round 10
// 221.969 us; speedup vs baseline: 1.0574x; 1.0574x over previous
//
#include <hip/hip_runtime.h>

using bf16 = __bf16;
typedef bf16 bf16x4 __attribute__((ext_vector_type(4)));
typedef bf16 bf16x8 __attribute__((ext_vector_type(8)));
typedef float f32x4 __attribute__((ext_vector_type(4)));

// ---------------------------------------------------------------- helpers
// GEMM LDS tiles: row stride 192 bf16 (384B, bank-aligned). XOR row&7 into
// element bits [3:5] -> 8 distinct 16B slots per 8 rows.
__device__ __forceinline__ int swz192(int row, int col) {
  return row * 192 + (col ^ ((row & 7) << 3));
}
// attention k tile: 256 rows x 32 bf16 (64B rows). Pack 2 rows per 128B block,
// XOR (row>>1)&3 into col bits [3:4].
__device__ __forceinline__ int qk_idx(int row, int col) {
  return (row >> 1) * 64 + (row & 1) * 32 + (col ^ (((row >> 1) & 3) << 3));
}
// V^T tile: 32 rows(d) x 256 bf16. Rotate n by 16*(d>>3); XOR (d&7)<<3
// (bank conflicts 3.5M -> 0.96M measured in r4).
__device__ __forceinline__ int vt_idx(int d, int n) {
  return d * 256 + (((n + ((d >> 3) << 4)) & 255) ^ ((d & 7) << 3));
}
// P tile (per wave): 16 rows x 64 bf16 (K=64 quarter) -> XOR r&7 into 16B slots.
__device__ __forceinline__ int p_idx4(int wv, int r, int c) {
  return wv * 1024 + r * 64 + (c ^ ((r & 7) << 3));
}

#define LOG2E 1.44269504088896f

// ---------------------------------------------------------------- f32->bf16 convert
// One-time pre-convert so GEMM staging is pure bf16x8 loads (no cvt VALU).
// n must be divisible by 8*256*grid stride-free: exact grids used below.
__global__ void k_conv8(const float* __restrict__ in, bf16* __restrict__ o) {
  const int i = (blockIdx.x * 256 + threadIdx.x) * 8;
  const f32x4 a = *reinterpret_cast<const f32x4*>(&in[i]);
  const f32x4 b = *reinterpret_cast<const f32x4*>(&in[i + 4]);
  bf16x8 v;
  v[0] = (bf16)a[0]; v[1] = (bf16)a[1]; v[2] = (bf16)a[2]; v[3] = (bf16)a[3];
  v[4] = (bf16)b[0]; v[5] = (bf16)b[1]; v[6] = (bf16)b[2]; v[7] = (bf16)b[3];
  *reinterpret_cast<bf16x8*>(&o[i]) = v;
}

// ---------------------------------------------------------------- GEMM
// out[m][n] = sum_k A[m][k] * W[n][k] + bias[n];  K = 192 staged whole.
// BM=64, BN=64 (r9: 48KB LDS -> 3 blocks/CU, measured -6us vs 128x64).
// A and W both bf16 (pre-converted) -> staging = 12x16B loads + 12 ds_writes
// per thread, zero convert VALU (r10). 4 waves 2x2, wave = 32x32.
// XCD-co-locating 1D swizzle (r8): x=bid&7, j=bid>>3, m=x+8*(j/NT), n=j%NT.
// NORM_QK: q cols (<192): L2-normalize per-head 32-dim group AND pre-multiply
// by log2e * exp(min(logit_scale,log 100)); k cols ([192,384)): norm only.
template <bool OUT_F32, bool NORM_QK, int NT>
__global__ __launch_bounds__(256) void k_gemm(const bf16* __restrict__ A,
                                              const bf16* __restrict__ W,
                                              const float* __restrict__ bias,
                                              const float* __restrict__ lsc,
                                              void* __restrict__ Op, int Ntot) {
  __shared__ bf16 As[64 * 192];
  __shared__ bf16 Bs[64 * 192];
  const int bid = blockIdx.x;
  const int xcd = bid & 7;
  const int j = bid >> 3;
  const int m0 = (xcd + 8 * (j / NT)) * 64;
  const int n0 = (j % NT) * 64;
  const int t = threadIdx.x;

#pragma unroll
  for (int i = 0; i < 6; ++i) {
    int f = t + i * 256;
    int row = f / 24, c8 = f % 24;
    bf16x8 v = *reinterpret_cast<const bf16x8*>(&A[(m0 + row) * 192 + c8 * 8]);
    *reinterpret_cast<bf16x8*>(&As[swz192(row, c8 * 8)]) = v;
  }
#pragma unroll
  for (int i = 0; i < 6; ++i) {
    int f = t + i * 256;
    int row = f / 24, c8 = f % 24;
    bf16x8 v = *reinterpret_cast<const bf16x8*>(&W[(n0 + row) * 192 + c8 * 8]);
    *reinterpret_cast<bf16x8*>(&Bs[swz192(row, c8 * 8)]) = v;
  }
  __syncthreads();

  const int w = t >> 6, lane = t & 63, lo = lane & 15, hi = lane >> 4;
  const int wm = (w >> 1) * 32, wn = (w & 1) * 32;
  f32x4 acc[2][2];
#pragma unroll
  for (int a = 0; a < 2; ++a)
#pragma unroll
    for (int c = 0; c < 2; ++c) acc[a][c] = f32x4{0.f, 0.f, 0.f, 0.f};

#pragma unroll
  for (int ks = 0; ks < 6; ++ks) {
    const int k0 = ks * 32 + hi * 8;
    bf16x8 af[2], bfr[2];
#pragma unroll
    for (int ri = 0; ri < 2; ++ri)
      af[ri] = *reinterpret_cast<const bf16x8*>(&As[swz192(wm + ri * 16 + lo, k0)]);
#pragma unroll
    for (int ci = 0; ci < 2; ++ci)
      bfr[ci] = *reinterpret_cast<const bf16x8*>(&Bs[swz192(wn + ci * 16 + lo, k0)]);
#pragma unroll
    for (int ri = 0; ri < 2; ++ri)
#pragma unroll
      for (int ci = 0; ci < 2; ++ci)
        acc[ri][ci] = __builtin_amdgcn_mfma_f32_16x16x32_bf16(af[ri], bfr[ci], acc[ri][ci], 0, 0, 0);
  }

  if (NORM_QK) {
    const int cb = n0 + wn;           // wave's 32-col block start (one head group)
    const bool donorm = (cb < 384);   // q or k
    float smul = 1.f;
    if (cb < 192)                     // q: fold logit scale AND log2e (exp->exp2)
      smul = expf(fminf(lsc[cb >> 5], 4.605170185988091f)) * LOG2E;
    const int col0 = cb + lo;
    const float b0 = bias[col0], b1 = bias[col0 + 16];
    bf16* O = (bf16*)Op;
#pragma unroll
    for (int ri = 0; ri < 2; ++ri)
#pragma unroll
      for (int rr = 0; rr < 4; ++rr) {
        float v0 = acc[ri][0][rr] + b0;
        float v1 = acc[ri][1][rr] + b1;
        if (donorm) {
          float ss = v0 * v0 + v1 * v1;
          ss += __shfl_xor(ss, 1, 16);
          ss += __shfl_xor(ss, 2, 16);
          ss += __shfl_xor(ss, 4, 16);
          ss += __shfl_xor(ss, 8, 16);
          const float rn = smul / fmaxf(sqrtf(ss), 1e-12f);
          v0 *= rn;
          v1 *= rn;
        }
        const int row = m0 + wm + ri * 16 + hi * 4 + rr;
        O[row * Ntot + col0] = (bf16)v0;
        O[row * Ntot + col0 + 16] = (bf16)v1;
      }
  } else {
#pragma unroll
    for (int ri = 0; ri < 2; ++ri)
#pragma unroll
      for (int ci = 0; ci < 2; ++ci) {
        const int col = n0 + wn + ci * 16 + lo;
        const float bv = bias[col];
#pragma unroll
        for (int rr = 0; rr < 4; ++rr) {
          const int row = m0 + wm + ri * 16 + hi * 4 + rr;
          const float val = acc[ri][ci][rr] + bv;
          if (OUT_F32)   // final output, never re-read: keep it out of L2
            __builtin_nontemporal_store(val, &((float*)Op)[row * Ntot + col]);
          else
            ((bf16*)Op)[row * Ntot + col] = (bf16)val;
        }
      }
  }
}

// ---------------------------------------------------------------- CPB MLP
// bt[r][h] = (relu(table[r] @ w1^T + b1) @ w2^T)[h]   (961 x 6)
__global__ void k_cpb1(const float* __restrict__ ct, const float* __restrict__ w1,
                       const float* __restrict__ b1, const float* __restrict__ w2,
                       float* __restrict__ bt) {
  int idx = blockIdx.x * 256 + threadIdx.x;
  if (idx >= 961 * 6) return;
  int r = idx / 6, hh = idx % 6;
  float t0 = ct[r * 2], t1 = ct[r * 2 + 1];
  float acc = 0.f;
  for (int j = 0; j < 512; ++j) {
    float hv = fmaf(w1[j * 2], t0, fmaf(w1[j * 2 + 1], t1, b1[j]));
    hv = fmaxf(hv, 0.f);
    acc = fmaf(hv, w2[hh * 512 + j], acc);
  }
  bt[idx] = acc;
}

// biasfT[h][j][i] = log2e * 16*sigmoid(bt[rel_index[i][j]][h])  -- TRANSPOSED, f32
__global__ void k_cpbT(const float* __restrict__ bt, const int* __restrict__ rel,
                       float* __restrict__ biasfT) {
  int idx = blockIdx.x * 256 + threadIdx.x;  // 6*65536 exactly
  int hh = idx >> 16;
  int jj = (idx >> 8) & 255;
  int i = idx & 255;
  float v = bt[rel[i * 256 + jj] * 6 + hh];
  biasfT[idx] = LOG2E * 16.f / (1.f + expf(-v));
}

// maskT[mb][j][i] = (bf16)(log2e * mask[mb][i][j])  -- LDS-tiled 64x64 transpose
__global__ __launch_bounds__(256) void k_maskT(const float* __restrict__ m,
                                               bf16* __restrict__ o) {
  __shared__ float tile[64][65];
  const int mb = blockIdx.y;
  const int it = blockIdx.x >> 2, jt = blockIdx.x & 3;
  const int tx = threadIdx.x & 63, ty = threadIdx.x >> 6;
  const float* mp = m + mb * 65536;
#pragma unroll
  for (int rr = 0; rr < 16; ++rr)
    tile[rr * 4 + ty][tx] = mp[(it * 64 + rr * 4 + ty) * 256 + jt * 64 + tx];
  __syncthreads();
  bf16* op = o + mb * 65536;
#pragma unroll
  for (int rr = 0; rr < 16; ++rr)
    op[(jt * 64 + rr * 4 + ty) * 256 + it * 64 + tx] = (bf16)(LOG2E * tile[tx][rr * 4 + ty]);
}

// ---------------------------------------------------------------- attention
// r8 version verbatim (known-good 109.4us, VGPR 128): one block per (b,h),
// XCD-pinned; 4 waves; LDS 40KB; max-free fused exp2 softmax; addend loads
// register-pipelined one phase ahead; plain cached loads.
__global__ __launch_bounds__(256) void k_attn(const bf16* __restrict__ qkv,
                                              const bf16* __restrict__ maskT,
                                              const float* __restrict__ biasfT,
                                              bf16* __restrict__ aout) {
  __shared__ bf16 ksh[256 * 32];   // 16 KB
  __shared__ bf16 vts[32 * 256];   // 16 KB
  __shared__ bf16 ps[4 * 16 * 64]; //  8 KB

  // ---- XCD-aware remap (bijective): bid -> (b, h)
  const int bid = blockIdx.x;
  const int x = bid & 7, i = bid >> 3;       // i in [0,192)
  const int mb = x * 8 + i / 24;             // 8 masks per XCD
  const int rem = i % 24;
  const int b = (rem / 6) * 64 + mb;         // b & 63 == mb
  const int h = rem % 6;
  const int t = threadIdx.x;

  // ---- staging (k, v): rows t>>2 (+p*64), 16B chunk t&3
  const int rsub = t >> 2;
  const int c4s = t & 3;
#pragma unroll
  for (int p = 0; p < 4; ++p) {
    const int row = p * 64 + rsub;
    const int base = (b * 256 + row) * 576 + h * 32 + c4s * 8;
    *reinterpret_cast<bf16x8*>(&ksh[qk_idx(row, c4s * 8)]) =
        *reinterpret_cast<const bf16x8*>(&qkv[base + 192]);
    bf16x8 v = *reinterpret_cast<const bf16x8*>(&qkv[base + 384]);
#pragma unroll
    for (int jj = 0; jj < 8; ++jj) vts[vt_idx(c4s * 8 + jj, row)] = v[jj];
  }
  __syncthreads();

  const int w = t >> 6, lane = t & 63, lo = lane & 15, hi = lane >> 4;
  const float* bT = biasfT + (h << 16);
  const bf16* mT = maskT + (mb << 16);
  const bf16* qbase = qkv + (b * 256) * 576 + h * 32;

  // prefetch q fragment for the wave's first row group
  bf16x8 afn = *reinterpret_cast<const bf16x8*>(&qbase[(w * 16 + lo) * 576 + hi * 8]);

  // addend prefetch for rgi=0, ph=0
  f32x4 bvp[4];
  bf16x4 mvp[4];
  {
    const int rbase0 = w * 16 + hi * 4;
#pragma unroll
    for (int c = 0; c < 4; ++c) {
      const int col = c * 16 + lo;
      bvp[c] = *reinterpret_cast<const f32x4*>(&bT[col * 256 + rbase0]);
      mvp[c] = *reinterpret_cast<const bf16x4*>(&mT[col * 256 + rbase0]);
    }
  }

  for (int rgi = 0; rgi < 4; ++rgi) {
    const int rg = rgi * 4 + w;  // this wave's 16-row group; private -> no barriers
    const int rbase = rg * 16 + hi * 4;
    const bf16x8 af = afn;
    if (rgi < 3)  // issue next q load early (off the critical path)
      afn = *reinterpret_cast<const bf16x8*>(&qbase[((rg + 4) * 16 + lo) * 576 + hi * 8]);

    f32x4 po0 = {0.f, 0.f, 0.f, 0.f}, po1 = {0.f, 0.f, 0.f, 0.f};
    float sum[4] = {0.f, 0.f, 0.f, 0.f};

#pragma unroll
    for (int ph = 0; ph < 4; ++ph) {
      // ---- consume this phase's prefetched addends
      f32x4 bv[4];
      bf16x4 mv[4];
#pragma unroll
      for (int c = 0; c < 4; ++c) { bv[c] = bvp[c]; mv[c] = mvp[c]; }
      // ---- issue NEXT phase's addend loads (hidden under MFMA+exp below)
      if (ph < 3) {
#pragma unroll
        for (int c = 0; c < 4; ++c) {
          const int col = (ph + 1) * 64 + c * 16 + lo;
          bvp[c] = *reinterpret_cast<const f32x4*>(&bT[col * 256 + rbase]);
          mvp[c] = *reinterpret_cast<const bf16x4*>(&mT[col * 256 + rbase]);
        }
      } else if (rgi < 3) {  // first phase of the next row group (rbase+64)
#pragma unroll
        for (int c = 0; c < 4; ++c) {
          const int col = c * 16 + lo;
          bvp[c] = *reinterpret_cast<const f32x4*>(&bT[col * 256 + rbase + 64]);
          mvp[c] = *reinterpret_cast<const bf16x4*>(&mT[col * 256 + rbase + 64]);
        }
      }
      // ---- k fragments + S MFMAs
      bf16x8 kf[4];
#pragma unroll
      for (int c4i = 0; c4i < 4; ++c4i) {
        const int ct = ph * 4 + c4i;
        kf[c4i] = *reinterpret_cast<const bf16x8*>(&ksh[qk_idx(ct * 16 + lo, hi * 8)]);
      }
      f32x4 a[4];
#pragma unroll
      for (int c4i = 0; c4i < 4; ++c4i) {
        f32x4 z = {0.f, 0.f, 0.f, 0.f};
        a[c4i] = __builtin_amdgcn_mfma_f32_16x16x32_bf16(af, kf[c4i], z, 0, 0, 0);
      }
      // ---- fused addend+exp2+sum+p-store (unnormalized)
#pragma unroll
      for (int c4i = 0; c4i < 4; ++c4i)
#pragma unroll
        for (int rr = 0; rr < 4; ++rr) {
          const float s = a[c4i][rr] + bv[c4i][rr] + (float)mv[c4i][rr];
          const float p = exp2f(s);
          sum[rr] += p;
          ps[p_idx4(w, hi * 4 + rr, c4i * 16 + lo)] = (bf16)p;
        }
      // ---- PV quarter (same-wave LDS producer/consumer; no barrier)
#pragma unroll
      for (int kb = 0; kb < 2; ++kb) {
        const bf16x8 pa = *reinterpret_cast<const bf16x8*>(&ps[p_idx4(w, lo, kb * 32 + hi * 8)]);
        const bf16x8 b0 = *reinterpret_cast<const bf16x8*>(&vts[vt_idx(lo, ph * 64 + kb * 32 + hi * 8)]);
        const bf16x8 b1 = *reinterpret_cast<const bf16x8*>(&vts[vt_idx(16 + lo, ph * 64 + kb * 32 + hi * 8)]);
        po0 = __builtin_amdgcn_mfma_f32_16x16x32_bf16(pa, b0, po0, 0, 0, 0);
        po1 = __builtin_amdgcn_mfma_f32_16x16x32_bf16(pa, b1, po1, 0, 0, 0);
      }
    }
    // ---- row-sum reduce across the 16 col-lanes, then normalize po
#pragma unroll
    for (int rr = 0; rr < 4; ++rr) {
      float s = sum[rr];
      s += __shfl_xor(s, 1, 16);
      s += __shfl_xor(s, 2, 16);
      s += __shfl_xor(s, 4, 16);
      s += __shfl_xor(s, 8, 16);
      sum[rr] = 1.f / s;
    }
    // ---- write attn-out (b, n, h*32+d) bf16
#pragma unroll
    for (int rr = 0; rr < 4; ++rr) {
      const int ob = (b * 256 + rbase + rr) * 192 + h * 32;
      aout[ob + lo] = (bf16)(po0[rr] * sum[rr]);
      aout[ob + 16 + lo] = (bf16)(po1[rr] * sum[rr]);
    }
  }
}

// ---------------------------------------------------------------- launcher
extern "C" void kernel_launch(void* const* d_in, const int* in_sizes, int n_in,
                              void* d_out, int out_size, void* d_ws, size_t ws_size,
                              hipStream_t stream) {
  const float* x      = (const float*)d_in[0];
  const float* mask   = (const float*)d_in[1];
  const float* qkv_w  = (const float*)d_in[2];
  const float* qkv_b  = (const float*)d_in[3];
  const float* proj_w = (const float*)d_in[4];
  const float* proj_b = (const float*)d_in[5];
  const float* lsc    = (const float*)d_in[6];
  const float* cpb_w1 = (const float*)d_in[7];
  const float* cpb_b1 = (const float*)d_in[8];
  const float* cpb_w2 = (const float*)d_in[9];
  const float* ctab   = (const float*)d_in[10];
  const int*   relidx = (const int*)d_in[11];

  char* ws = (char*)d_ws;
  bf16*  qkvb   = (bf16*)(ws);                      // 65536*576*2 = 75,497,472
  // xb and aoutb SHARE this slot (disjoint lifetimes, stream-ordered):
  // xb: written by k_conv8, read by QKV GEMM; aoutb: written by attn (later).
  bf16*  xb     = (bf16*)(ws + 75497472);           // 12582912*2  = 25,165,824
  bf16*  aoutb  = (bf16*)(ws + 75497472);           // 65536*192*2 = 25,165,824
  float* biasfT = (float*)(ws + 100663296);         // 6*65536*4   =  1,572,864  (transposed, x log2e)
  bf16*  maskTb = (bf16*)(ws + 102236160);          // 64*65536*2  =  8,388,608  (transposed, x log2e)
  float* bt     = (float*)(ws + 110624768);         // 961*6*4     =     23,064
  bf16*  qkv_wb = (bf16*)(ws + 110647840);          // 576*192*2   =    221,184
  bf16*  proj_wb= (bf16*)(ws + 110869024);          // 192*192*2   =     73,728

  k_conv8<<<6144, 256, 0, stream>>>(x, xb);             // 12,582,912 / (256*8)
  k_conv8<<<54, 256, 0, stream>>>(qkv_w, qkv_wb);       //    110,592 / (256*8)
  k_conv8<<<18, 256, 0, stream>>>(proj_w, proj_wb);     //     36,864 / (256*8)
  k_gemm<false, true, 9><<<9216, 256, 0, stream>>>(xb, qkv_wb, qkv_b, lsc, qkvb, 576);
  k_cpb1<<<23, 256, 0, stream>>>(ctab, cpb_w1, cpb_b1, cpb_w2, bt);
  k_cpbT<<<1536, 256, 0, stream>>>(bt, relidx, biasfT);
  k_maskT<<<dim3(16, 64), 256, 0, stream>>>(mask, maskTb);
  k_attn<<<1536, 256, 0, stream>>>(qkvb, maskTb, biasfT, aoutb);
  k_gemm<true, false, 3><<<3072, 256, 0, stream>>>(aoutb, proj_wb, proj_b, nullptr,
                                                   (float*)d_out, 192);
}

// Round 11
// 212.446 us; speedup vs baseline: 1.1048x; 1.0448x over previous
//
#include <hip/hip_runtime.h>

using bf16 = __bf16;
typedef bf16 bf16x4 __attribute__((ext_vector_type(4)));
typedef bf16 bf16x8 __attribute__((ext_vector_type(8)));
typedef float f32x4 __attribute__((ext_vector_type(4)));

// ---------------------------------------------------------------- helpers
// GEMM LDS tiles: row stride 192 bf16 (384B, bank-aligned). XOR row&7 into
// element bits [3:5] -> 8 distinct 16B slots per 8 rows.
__device__ __forceinline__ int swz192(int row, int col) {
  return row * 192 + (col ^ ((row & 7) << 3));
}
// attention k tile: 256 rows x 32 bf16 (64B rows). Pack 2 rows per 128B block,
// XOR (row>>1)&3 into col bits [3:4].
__device__ __forceinline__ int qk_idx(int row, int col) {
  return (row >> 1) * 64 + (row & 1) * 32 + (col ^ (((row >> 1) & 3) << 3));
}
// V^T tile: 32 rows(d) x 256 bf16. Rotate n by 16*(d>>3); XOR (d&7)<<3
// (bank conflicts 3.5M -> 0.96M measured in r4).
__device__ __forceinline__ int vt_idx(int d, int n) {
  return d * 256 + (((n + ((d >> 3) << 4)) & 255) ^ ((d & 7) << 3));
}
// P tile (per wave): 16 rows x 64 bf16 (K=64 quarter) -> XOR r&7 into 16B slots.
__device__ __forceinline__ int p_idx4(int wv, int r, int c) {
  return wv * 1024 + r * 64 + (c ^ ((r & 7) << 3));
}

#define LOG2E 1.44269504088896f
#define GLOAD_LDS(src, dst)                                                     \
  __builtin_amdgcn_global_load_lds(                                             \
      (const __attribute__((address_space(1))) void*)(src),                     \
      (__attribute__((address_space(3))) void*)(dst), 16, 0, 0)

// ---------------------------------------------------------------- GEMM
// out[m][n] = sum_k A[m][k] * W[n][k] + bias[n];  K = 192 staged whole.
// BM=64, BN=64, bf16 operands (pre-converted). r11: staging via
// global_load_lds width=16 — linear LDS dest (wave-uniform base + lane*16B),
// XOR swizzle realized by PRE-SWIZZLING the per-lane GLOBAL source chunk
// (c8 ^ (row&7) permutes within aligned 8-chunk groups -> rule #21 safe).
// XCD-co-locating 1D swizzle (r8): x=bid&7, j=bid>>3, m=x+8*(j/NT), n=j%NT.
// NORM_QK: q cols (<192): L2-normalize per-head 32-dim group AND pre-multiply
// by log2e * exp(min(logit_scale,log 100)); k cols ([192,384)): norm only.
template <bool OUT_F32, bool NORM_QK, int NT>
__global__ __launch_bounds__(256) void k_gemm(const bf16* __restrict__ A,
                                              const bf16* __restrict__ W,
                                              const float* __restrict__ bias,
                                              const float* __restrict__ lsc,
                                              void* __restrict__ Op, int Ntot) {
  __shared__ bf16 As[64 * 192];
  __shared__ bf16 Bs[64 * 192];
  const int bid = blockIdx.x;
  const int xcd = bid & 7;
  const int j = bid >> 3;
  const int m0 = (xcd + 8 * (j / NT)) * 64;
  const int n0 = (j % NT) * 64;
  const int t = threadIdx.x;

#pragma unroll
  for (int i = 0; i < 6; ++i) {
    const int f = t + i * 256;
    const int row = f / 24, c8 = f % 24;
    const int csw = (c8 ^ (row & 7)) * 8;  // pre-swizzled source chunk
    GLOAD_LDS(&A[(m0 + row) * 192 + csw], &As[f * 8]);
    GLOAD_LDS(&W[(n0 + row) * 192 + csw], &Bs[f * 8]);
  }
  __syncthreads();

  const int w = t >> 6, lane = t & 63, lo = lane & 15, hi = lane >> 4;
  const int wm = (w >> 1) * 32, wn = (w & 1) * 32;
  f32x4 acc[2][2];
#pragma unroll
  for (int a = 0; a < 2; ++a)
#pragma unroll
    for (int c = 0; c < 2; ++c) acc[a][c] = f32x4{0.f, 0.f, 0.f, 0.f};

#pragma unroll
  for (int ks = 0; ks < 6; ++ks) {
    const int k0 = ks * 32 + hi * 8;
    bf16x8 af[2], bfr[2];
#pragma unroll
    for (int ri = 0; ri < 2; ++ri)
      af[ri] = *reinterpret_cast<const bf16x8*>(&As[swz192(wm + ri * 16 + lo, k0)]);
#pragma unroll
    for (int ci = 0; ci < 2; ++ci)
      bfr[ci] = *reinterpret_cast<const bf16x8*>(&Bs[swz192(wn + ci * 16 + lo, k0)]);
#pragma unroll
    for (int ri = 0; ri < 2; ++ri)
#pragma unroll
      for (int ci = 0; ci < 2; ++ci)
        acc[ri][ci] = __builtin_amdgcn_mfma_f32_16x16x32_bf16(af[ri], bfr[ci], acc[ri][ci], 0, 0, 0);
  }

  if (NORM_QK) {
    const int cb = n0 + wn;           // wave's 32-col block start (one head group)
    const bool donorm = (cb < 384);   // q or k
    float smul = 1.f;
    if (cb < 192)                     // q: fold logit scale AND log2e (exp->exp2)
      smul = expf(fminf(lsc[cb >> 5], 4.605170185988091f)) * LOG2E;
    const int col0 = cb + lo;
    const float b0 = bias[col0], b1 = bias[col0 + 16];
    bf16* O = (bf16*)Op;
#pragma unroll
    for (int ri = 0; ri < 2; ++ri)
#pragma unroll
      for (int rr = 0; rr < 4; ++rr) {
        float v0 = acc[ri][0][rr] + b0;
        float v1 = acc[ri][1][rr] + b1;
        if (donorm) {
          float ss = v0 * v0 + v1 * v1;
          ss += __shfl_xor(ss, 1, 16);
          ss += __shfl_xor(ss, 2, 16);
          ss += __shfl_xor(ss, 4, 16);
          ss += __shfl_xor(ss, 8, 16);
          const float rn = smul / fmaxf(sqrtf(ss), 1e-12f);
          v0 *= rn;
          v1 *= rn;
        }
        const int row = m0 + wm + ri * 16 + hi * 4 + rr;
        O[row * Ntot + col0] = (bf16)v0;
        O[row * Ntot + col0 + 16] = (bf16)v1;
      }
  } else {
#pragma unroll
    for (int ri = 0; ri < 2; ++ri)
#pragma unroll
      for (int ci = 0; ci < 2; ++ci) {
        const int col = n0 + wn + ci * 16 + lo;
        const float bv = bias[col];
#pragma unroll
        for (int rr = 0; rr < 4; ++rr) {
          const int row = m0 + wm + ri * 16 + hi * 4 + rr;
          const float val = acc[ri][ci][rr] + bv;
          if (OUT_F32)   // final output, never re-read: keep it out of L2
            __builtin_nontemporal_store(val, &((float*)Op)[row * Ntot + col]);
          else
            ((bf16*)Op)[row * Ntot + col] = (bf16)val;
        }
      }
  }
}

// ---------------------------------------------------------------- CPB MLP
// bt[r][h] = (relu(table[r] @ w1^T + b1) @ w2^T)[h]   (961 x 6)
__global__ void k_cpb1(const float* __restrict__ ct, const float* __restrict__ w1,
                       const float* __restrict__ b1, const float* __restrict__ w2,
                       float* __restrict__ bt) {
  int idx = blockIdx.x * 256 + threadIdx.x;
  if (idx >= 961 * 6) return;
  int r = idx / 6, hh = idx % 6;
  float t0 = ct[r * 2], t1 = ct[r * 2 + 1];
  float acc = 0.f;
  for (int j = 0; j < 512; ++j) {
    float hv = fmaf(w1[j * 2], t0, fmaf(w1[j * 2 + 1], t1, b1[j]));
    hv = fmaxf(hv, 0.f);
    acc = fmaf(hv, w2[hh * 512 + j], acc);
  }
  bt[idx] = acc;
}

// ---------------------------------------------------------------- fused prep
// Range-dispatched single kernel (r11: launch consolidation 9->5):
//   [0, 6144)        conv8 x -> xb            (12,582,912 f32)
//   [6144, 6198)     conv8 qkv_w -> qkv_wb    (   110,592 f32)
//   [6198, 6216)     conv8 proj_w -> proj_wb  (    36,864 f32)
//   [6216, 7240)     maskT (LDS-tiled 64x64 transpose, x log2e, bf16)
//   [7240, 8776)     cpbT (bias table gather+sigmoid, transposed, x log2e)
// cpbT depends on bt -> launch AFTER k_cpb1 (stream-ordered).
__global__ __launch_bounds__(256) void k_prep(
    const float* __restrict__ x, bf16* __restrict__ xb,
    const float* __restrict__ qkv_w, bf16* __restrict__ qkv_wb,
    const float* __restrict__ proj_w, bf16* __restrict__ proj_wb,
    const float* __restrict__ mask, bf16* __restrict__ maskT,
    const float* __restrict__ bt, const int* __restrict__ rel,
    float* __restrict__ biasfT) {
  __shared__ float tile[64][65];
  const int bid = blockIdx.x;
  if (bid < 6216) {
    // ---- f32 -> bf16 convert, 8 elements/thread
    const float* in;
    bf16* o;
    int vb;
    if (bid < 6144) { in = x; o = xb; vb = bid; }
    else if (bid < 6198) { in = qkv_w; o = qkv_wb; vb = bid - 6144; }
    else { in = proj_w; o = proj_wb; vb = bid - 6198; }
    const int i = (vb * 256 + threadIdx.x) * 8;
    const f32x4 a = *reinterpret_cast<const f32x4*>(&in[i]);
    const f32x4 b = *reinterpret_cast<const f32x4*>(&in[i + 4]);
    bf16x8 v;
    v[0] = (bf16)a[0]; v[1] = (bf16)a[1]; v[2] = (bf16)a[2]; v[3] = (bf16)a[3];
    v[4] = (bf16)b[0]; v[5] = (bf16)b[1]; v[6] = (bf16)b[2]; v[7] = (bf16)b[3];
    *reinterpret_cast<bf16x8*>(&o[i]) = v;
  } else if (bid < 7240) {
    // ---- maskT[mb][j][i] = (bf16)(log2e * mask[mb][i][j])
    const int rem = bid - 6216;
    const int mb = rem >> 4;
    const int it = (rem & 15) >> 2, jt = rem & 3;
    const int tx = threadIdx.x & 63, ty = threadIdx.x >> 6;
    const float* mp = mask + mb * 65536;
#pragma unroll
    for (int rr = 0; rr < 16; ++rr)
      tile[rr * 4 + ty][tx] = mp[(it * 64 + rr * 4 + ty) * 256 + jt * 64 + tx];
    __syncthreads();
    bf16* op = maskT + mb * 65536;
#pragma unroll
    for (int rr = 0; rr < 16; ++rr)
      op[(jt * 64 + rr * 4 + ty) * 256 + it * 64 + tx] = (bf16)(LOG2E * tile[tx][rr * 4 + ty]);
  } else {
    // ---- biasfT[h][j][i] = log2e * 16*sigmoid(bt[rel[i][j]][h])
    const int idx = (bid - 7240) * 256 + threadIdx.x;  // 6*65536 exactly
    const int hh = idx >> 16;
    const int jj = (idx >> 8) & 255;
    const int i = idx & 255;
    const float v = bt[rel[i * 256 + jj] * 6 + hh];
    biasfT[idx] = LOG2E * 16.f / (1.f + expf(-v));
  }
}

// ---------------------------------------------------------------- attention
// r8 version verbatim (known-good 109.4us, VGPR 128): one block per (b,h),
// XCD-pinned; 4 waves; LDS 40KB; max-free fused exp2 softmax; addend loads
// register-pipelined one phase ahead; plain cached loads.
__global__ __launch_bounds__(256) void k_attn(const bf16* __restrict__ qkv,
                                              const bf16* __restrict__ maskT,
                                              const float* __restrict__ biasfT,
                                              bf16* __restrict__ aout) {
  __shared__ bf16 ksh[256 * 32];   // 16 KB
  __shared__ bf16 vts[32 * 256];   // 16 KB
  __shared__ bf16 ps[4 * 16 * 64]; //  8 KB

  // ---- XCD-aware remap (bijective): bid -> (b, h)
  const int bid = blockIdx.x;
  const int x = bid & 7, i = bid >> 3;       // i in [0,192)
  const int mb = x * 8 + i / 24;             // 8 masks per XCD
  const int rem = i % 24;
  const int b = (rem / 6) * 64 + mb;         // b & 63 == mb
  const int h = rem % 6;
  const int t = threadIdx.x;

  // ---- staging (k, v): rows t>>2 (+p*64), 16B chunk t&3
  const int rsub = t >> 2;
  const int c4s = t & 3;
#pragma unroll
  for (int p = 0; p < 4; ++p) {
    const int row = p * 64 + rsub;
    const int base = (b * 256 + row) * 576 + h * 32 + c4s * 8;
    *reinterpret_cast<bf16x8*>(&ksh[qk_idx(row, c4s * 8)]) =
        *reinterpret_cast<const bf16x8*>(&qkv[base + 192]);
    bf16x8 v = *reinterpret_cast<const bf16x8*>(&qkv[base + 384]);
#pragma unroll
    for (int jj = 0; jj < 8; ++jj) vts[vt_idx(c4s * 8 + jj, row)] = v[jj];
  }
  __syncthreads();

  const int w = t >> 6, lane = t & 63, lo = lane & 15, hi = lane >> 4;
  const float* bT = biasfT + (h << 16);
  const bf16* mT = maskT + (mb << 16);
  const bf16* qbase = qkv + (b * 256) * 576 + h * 32;

  // prefetch q fragment for the wave's first row group
  bf16x8 afn = *reinterpret_cast<const bf16x8*>(&qbase[(w * 16 + lo) * 576 + hi * 8]);

  // addend prefetch for rgi=0, ph=0
  f32x4 bvp[4];
  bf16x4 mvp[4];
  {
    const int rbase0 = w * 16 + hi * 4;
#pragma unroll
    for (int c = 0; c < 4; ++c) {
      const int col = c * 16 + lo;
      bvp[c] = *reinterpret_cast<const f32x4*>(&bT[col * 256 + rbase0]);
      mvp[c] = *reinterpret_cast<const bf16x4*>(&mT[col * 256 + rbase0]);
    }
  }

  for (int rgi = 0; rgi < 4; ++rgi) {
    const int rg = rgi * 4 + w;  // this wave's 16-row group; private -> no barriers
    const int rbase = rg * 16 + hi * 4;
    const bf16x8 af = afn;
    if (rgi < 3)  // issue next q load early (off the critical path)
      afn = *reinterpret_cast<const bf16x8*>(&qbase[((rg + 4) * 16 + lo) * 576 + hi * 8]);

    f32x4 po0 = {0.f, 0.f, 0.f, 0.f}, po1 = {0.f, 0.f, 0.f, 0.f};
    float sum[4] = {0.f, 0.f, 0.f, 0.f};

#pragma unroll
    for (int ph = 0; ph < 4; ++ph) {
      // ---- consume this phase's prefetched addends
      f32x4 bv[4];
      bf16x4 mv[4];
#pragma unroll
      for (int c = 0; c < 4; ++c) { bv[c] = bvp[c]; mv[c] = mvp[c]; }
      // ---- issue NEXT phase's addend loads (hidden under MFMA+exp below)
      if (ph < 3) {
#pragma unroll
        for (int c = 0; c < 4; ++c) {
          const int col = (ph + 1) * 64 + c * 16 + lo;
          bvp[c] = *reinterpret_cast<const f32x4*>(&bT[col * 256 + rbase]);
          mvp[c] = *reinterpret_cast<const bf16x4*>(&mT[col * 256 + rbase]);
        }
      } else if (rgi < 3) {  // first phase of the next row group (rbase+64)
#pragma unroll
        for (int c = 0; c < 4; ++c) {
          const int col = c * 16 + lo;
          bvp[c] = *reinterpret_cast<const f32x4*>(&bT[col * 256 + rbase + 64]);
          mvp[c] = *reinterpret_cast<const bf16x4*>(&mT[col * 256 + rbase + 64]);
        }
      }
      // ---- k fragments + S MFMAs
      bf16x8 kf[4];
#pragma unroll
      for (int c4i = 0; c4i < 4; ++c4i) {
        const int ct = ph * 4 + c4i;
        kf[c4i] = *reinterpret_cast<const bf16x8*>(&ksh[qk_idx(ct * 16 + lo, hi * 8)]);
      }
      f32x4 a[4];
#pragma unroll
      for (int c4i = 0; c4i < 4; ++c4i) {
        f32x4 z = {0.f, 0.f, 0.f, 0.f};
        a[c4i] = __builtin_amdgcn_mfma_f32_16x16x32_bf16(af, kf[c4i], z, 0, 0, 0);
      }
      // ---- fused addend+exp2+sum+p-store (unnormalized)
#pragma unroll
      for (int c4i = 0; c4i < 4; ++c4i)
#pragma unroll
        for (int rr = 0; rr < 4; ++rr) {
          const float s = a[c4i][rr] + bv[c4i][rr] + (float)mv[c4i][rr];
          const float p = exp2f(s);
          sum[rr] += p;
          ps[p_idx4(w, hi * 4 + rr, c4i * 16 + lo)] = (bf16)p;
        }
      // ---- PV quarter (same-wave LDS producer/consumer; no barrier)
#pragma unroll
      for (int kb = 0; kb < 2; ++kb) {
        const bf16x8 pa = *reinterpret_cast<const bf16x8*>(&ps[p_idx4(w, lo, kb * 32 + hi * 8)]);
        const bf16x8 b0 = *reinterpret_cast<const bf16x8*>(&vts[vt_idx(lo, ph * 64 + kb * 32 + hi * 8)]);
        const bf16x8 b1 = *reinterpret_cast<const bf16x8*>(&vts[vt_idx(16 + lo, ph * 64 + kb * 32 + hi * 8)]);
        po0 = __builtin_amdgcn_mfma_f32_16x16x32_bf16(pa, b0, po0, 0, 0, 0);
        po1 = __builtin_amdgcn_mfma_f32_16x16x32_bf16(pa, b1, po1, 0, 0, 0);
      }
    }
    // ---- row-sum reduce across the 16 col-lanes, then normalize po
#pragma unroll
    for (int rr = 0; rr < 4; ++rr) {
      float s = sum[rr];
      s += __shfl_xor(s, 1, 16);
      s += __shfl_xor(s, 2, 16);
      s += __shfl_xor(s, 4, 16);
      s += __shfl_xor(s, 8, 16);
      sum[rr] = 1.f / s;
    }
    // ---- write attn-out (b, n, h*32+d) bf16
#pragma unroll
    for (int rr = 0; rr < 4; ++rr) {
      const int ob = (b * 256 + rbase + rr) * 192 + h * 32;
      aout[ob + lo] = (bf16)(po0[rr] * sum[rr]);
      aout[ob + 16 + lo] = (bf16)(po1[rr] * sum[rr]);
    }
  }
}

// ---------------------------------------------------------------- launcher
extern "C" void kernel_launch(void* const* d_in, const int* in_sizes, int n_in,
                              void* d_out, int out_size, void* d_ws, size_t ws_size,
                              hipStream_t stream) {
  const float* x      = (const float*)d_in[0];
  const float* mask   = (const float*)d_in[1];
  const float* qkv_w  = (const float*)d_in[2];
  const float* qkv_b  = (const float*)d_in[3];
  const float* proj_w = (const float*)d_in[4];
  const float* proj_b = (const float*)d_in[5];
  const float* lsc    = (const float*)d_in[6];
  const float* cpb_w1 = (const float*)d_in[7];
  const float* cpb_b1 = (const float*)d_in[8];
  const float* cpb_w2 = (const float*)d_in[9];
  const float* ctab   = (const float*)d_in[10];
  const int*   relidx = (const int*)d_in[11];

  char* ws = (char*)d_ws;
  bf16*  qkvb   = (bf16*)(ws);                      // 65536*576*2 = 75,497,472
  // xb and aoutb SHARE this slot (disjoint lifetimes, stream-ordered):
  bf16*  xb     = (bf16*)(ws + 75497472);           // 12582912*2  = 25,165,824
  bf16*  aoutb  = (bf16*)(ws + 75497472);           // 65536*192*2 = 25,165,824
  float* biasfT = (float*)(ws + 100663296);         // 6*65536*4   =  1,572,864  (transposed, x log2e)
  bf16*  maskTb = (bf16*)(ws + 102236160);          // 64*65536*2  =  8,388,608  (transposed, x log2e)
  float* bt     = (float*)(ws + 110624768);         // 961*6*4     =     23,064
  bf16*  qkv_wb = (bf16*)(ws + 110647840);          // 576*192*2   =    221,184
  bf16*  proj_wb= (bf16*)(ws + 110869024);          // 192*192*2   =     73,728

  k_cpb1<<<23, 256, 0, stream>>>(ctab, cpb_w1, cpb_b1, cpb_w2, bt);
  k_prep<<<8776, 256, 0, stream>>>(x, xb, qkv_w, qkv_wb, proj_w, proj_wb,
                                   mask, maskTb, bt, relidx, biasfT);
  k_gemm<false, true, 9><<<9216, 256, 0, stream>>>(xb, qkv_wb, qkv_b, lsc, qkvb, 576);
  k_attn<<<1536, 256, 0, stream>>>(qkvb, maskTb, biasfT, aoutb);
  k_gemm<true, false, 3><<<3072, 256, 0, stream>>>(aoutb, proj_wb, proj_b, nullptr,
                                                   (float*)d_out, 192);
}